// Round 2
// baseline (382.889 us; speedup 1.0000x reference)
//
#include <hip/hip_runtime.h>

#define NFEAT 2048
#define BATCH 16384

// One block per row. Stage the 2048-float row in LDS, gather from LDS.
// All 6 global loads per thread are issued BEFORE the barrier so the
// barrier's vmcnt(0) drain exposes only ONE memory latency per phase.
__global__ __launch_bounds__(256, 4) void swap_corrupt_kernel(
    const float* __restrict__ x,
    const int*   __restrict__ mask,
    const int*   __restrict__ perm,
    float*       __restrict__ out)
{
    __shared__ float row[NFEAT];

    const int t = threadIdx.x;
    const size_t base = (size_t)blockIdx.x * NFEAT;

    const float4* __restrict__ x4 = (const float4*)(x + base);
    const int4*   __restrict__ m4 = (const int4*)(mask + base);
    const int4*   __restrict__ p4 = (const int4*)(perm + base);
    float4*       __restrict__ o4 = (float4*)(out + base);

    // ---- issue ALL global loads up front (max memory-level parallelism) ----
    float4 a  = x4[t];
    float4 b  = x4[t + 256];
    int4   m1 = m4[t];
    int4   p1 = p4[t];
    int4   m2 = m4[t + 256];
    int4   p2 = p4[t + 256];

    // stage x into LDS (keep register copies for the non-swap path)
    ((float4*)row)[t]       = a;
    ((float4*)row)[t + 256] = b;
    __syncthreads();   // drains all outstanding loads once

    // ---- pure LDS-gather + select + store, no further global-load waits ----
    {
        float4 o;
        o.x = m1.x ? row[p1.x] : a.x;
        o.y = m1.y ? row[p1.y] : a.y;
        o.z = m1.z ? row[p1.z] : a.z;
        o.w = m1.w ? row[p1.w] : a.w;
        o4[t] = o;
    }
    {
        float4 o;
        o.x = m2.x ? row[p2.x] : b.x;
        o.y = m2.y ? row[p2.y] : b.y;
        o.z = m2.z ? row[p2.z] : b.z;
        o.w = m2.w ? row[p2.w] : b.w;
        o4[t + 256] = o;
    }
}

extern "C" void kernel_launch(void* const* d_in, const int* in_sizes, int n_in,
                              void* d_out, int out_size, void* d_ws, size_t ws_size,
                              hipStream_t stream) {
    const float* x    = (const float*)d_in[0];
    const int*   mask = (const int*)d_in[1];
    const int*   perm = (const int*)d_in[2];
    float*       out  = (float*)d_out;

    swap_corrupt_kernel<<<dim3(BATCH), dim3(256), 0, stream>>>(x, mask, perm, out);
}